// Round 14
// baseline (228.176 us; speedup 1.0000x reference)
//
#include <hip/hip_runtime.h>
#include <stdint.h>

// ---------------------------------------------------------------------------
// SNN EMNIST forward: T=10, B=4096, IN=784, HID=256, NCLS=47
// splitk (EXACT 3-way bf16 W1) -> fused spikegen+MFMA gemm -> fused scan+out.
// R14: the hash is HOISTED out of the K-loop into a per-thread prologue burst
// (R6/R12/R13 proved the wall is the per-iter hash<->MFMA phase serialization,
// invariant to hash codegen). Phase 1: each thread hashes all 25 slabs (200
// hashes, rolled, no barriers) -> 25 packed bytes to L2-resident scratch
// (own-thread write->read, no sync). Phase 2: pure-MFMA K-loop (expand byte
// ~15 VALU/iter, byte prefetched 1 iter ahead). Bits/staging/MFMA order
// untouched -> bitwise-identical output (absmax 4.882812e-4).
// ---------------------------------------------------------------------------

#define T_STEPS 10
#define BATCH   4096
#define IN_DIM  784
#define HID     256
#define NCLS    47
#define NROWS   (T_STEPS * BATCH)        // 40960
#define KWORDS  25                       // ceil(784/32)
#define KPAD    800                      // 25*32
#define NBLK    (NROWS / 64)             // 640 gemm blocks

// d_ws layout (bytes):
//   [0, 41943040)          I_all  : float [40960][256]
//   [41943040, 46039040)   spkb   : u8 [25][640][256]  (4,096,000 B, L2-res)
//   [46039040, ...)        W1{hi,mid,lo}T : bf16 [256][800], 409600 B each
#define WS_IALL_OFF 0u
#define WS_SPKB_OFF 41943040u
#define WS_W1HI_OFF 46039040u
#define WS_W1MD_OFF (46039040u + 409600u)
#define WS_W1LO_OFF (46039040u + 819200u)

typedef __attribute__((ext_vector_type(8))) short    bf16x8;
typedef __attribute__((ext_vector_type(4))) float    f32x4;
typedef __attribute__((ext_vector_type(4))) uint32_t u32x4;

// ---------------------------------------------------------------------------
// Threefry2x32, key=(0,42), partitionable: counter=(0, lo), out=(o0^o1)>>9.
// One asm block = whole hash (72 instrs), validated bitwise in R13.
// J42 = "42".."49" bakes element offset j into the first add.
// ---------------------------------------------------------------------------
#define TF_G1(x0, x1) \
    "v_add_u32 " x0 ", " x0 ", " x1 "\n\t" \
    "v_alignbit_b32 " x1 ", " x1 ", " x1 ", 19\n\t" \
    "v_xor_b32 " x1 ", " x1 ", " x0 "\n\t" \
    "v_add_u32 " x0 ", " x0 ", " x1 "\n\t" \
    "v_alignbit_b32 " x1 ", " x1 ", " x1 ", 17\n\t" \
    "v_xor_b32 " x1 ", " x1 ", " x0 "\n\t" \
    "v_add_u32 " x0 ", " x0 ", " x1 "\n\t" \
    "v_alignbit_b32 " x1 ", " x1 ", " x1 ", 6\n\t" \
    "v_xor_b32 " x1 ", " x1 ", " x0 "\n\t" \
    "v_add_u32 " x0 ", " x0 ", " x1 "\n\t" \
    "v_alignbit_b32 " x1 ", " x1 ", " x1 ", 26\n\t" \
    "v_xor_b32 " x1 ", " x1 ", " x0 "\n\t"

#define TF_G2(x0, x1) \
    "v_add_u32 " x0 ", " x0 ", " x1 "\n\t" \
    "v_alignbit_b32 " x1 ", " x1 ", " x1 ", 15\n\t" \
    "v_xor_b32 " x1 ", " x1 ", " x0 "\n\t" \
    "v_add_u32 " x0 ", " x0 ", " x1 "\n\t" \
    "v_alignbit_b32 " x1 ", " x1 ", " x1 ", 3\n\t" \
    "v_xor_b32 " x1 ", " x1 ", " x0 "\n\t" \
    "v_add_u32 " x0 ", " x0 ", " x1 "\n\t" \
    "v_alignbit_b32 " x1 ", " x1 ", " x1 ", 16\n\t" \
    "v_xor_b32 " x1 ", " x1 ", " x0 "\n\t" \
    "v_add_u32 " x0 ", " x0 ", " x1 "\n\t" \
    "v_alignbit_b32 " x1 ", " x1 ", " x1 ", 8\n\t" \
    "v_xor_b32 " x1 ", " x1 ", " x0 "\n\t"

#define TF_HASH9(m, ib, J42) do {                                   \
    uint32_t _x0, _x1;                                              \
    asm("v_add_u32 %1, " J42 ", %2\n\t"       /* x1 = ib + 42+j */  \
        "v_mov_b32 %0, %1\n\t"                /* R1: x0 += x1   */  \
        "v_alignbit_b32 %1, %1, %1, 19\n\t"                         \
        "v_xor_b32 %1, %1, %0\n\t"                                  \
        "v_add_u32 %0, %0, %1\n\t"            /* R2 */              \
        "v_alignbit_b32 %1, %1, %1, 17\n\t"                         \
        "v_xor_b32 %1, %1, %0\n\t"                                  \
        "v_add_u32 %0, %0, %1\n\t"            /* R3 */              \
        "v_alignbit_b32 %1, %1, %1, 6\n\t"                          \
        "v_xor_b32 %1, %1, %0\n\t"                                  \
        "v_add_u32 %0, %0, %1\n\t"            /* R4 */              \
        "v_alignbit_b32 %1, %1, %1, 26\n\t"                         \
        "v_xor_b32 %1, %1, %0\n\t"                                  \
        "v_add_u32 %0, 42, %0\n\t"            /* x0 += ks1 */       \
        "v_add_u32 %1, 0x1bd11bf1, %1\n\t"    /* x1 += ks2+1 */     \
        TF_G2("%0", "%1")                     /* R5-R8 */           \
        "v_add_u32 %0, 0x1bd11bf0, %0\n\t"    /* x0 += ks2 */       \
        "v_add_u32 %1, 2, %1\n\t"             /* x1 += ks0+2 */     \
        TF_G1("%0", "%1")                     /* R9-R12 */          \
        "v_add_u32 %1, 45, %1\n\t"            /* x1 += ks1+3 */     \
        TF_G2("%0", "%1")                     /* R13-R16 */         \
        "v_add_u32 %0, 42, %0\n\t"            /* x0 += ks1 */       \
        "v_add_u32 %1, 0x1bd11bf4, %1\n\t"    /* x1 += ks2+4 */     \
        TF_G1("%0", "%1")                     /* R17-R20 */         \
        "v_add_u32 %0, 0x1bd11bf0, %0\n\t"    /* x0 += ks2 */       \
        "v_add_u32 %1, 5, %1\n\t"             /* x1 += ks0+5 */     \
        "v_xor_b32 %0, %0, %1\n\t"            /* o0^o1 */           \
        "v_lshrrev_b32 %0, 9, %0"             /* >>9 */             \
        : "=&v"(_x0), "=&v"(_x1) : "v"(ib));                        \
    m = _x0;                                                        \
} while (0)

// ---------------------------------------------------------------------------
// Kernel B0: split W1 (f32 [784][256]) into transposed bf16 hi/mid/lo
// [256][800]. EXACT: hi+mid+lo == w bitwise.
// ---------------------------------------------------------------------------
__global__ __launch_bounds__(256) void splitk_k(
        const float* __restrict__ W1, ushort* __restrict__ hiT,
        ushort* __restrict__ midT, ushort* __restrict__ loT) {
    int n = blockIdx.x;                  // 0..255
    for (int k = threadIdx.x; k < KPAD; k += 256) {
        float w = (k < IN_DIM) ? W1[k * HID + n] : 0.0f;
        uint32_t u = __float_as_uint(w);
        uint32_t hb = (u + 0x7FFFu + ((u >> 16) & 1u)) >> 16;    // RNE to bf16
        float hf = __uint_as_float(hb << 16);
        float r1 = w - hf;                                       // exact
        uint32_t u1 = __float_as_uint(r1);
        uint32_t mb = (u1 + 0x7FFFu + ((u1 >> 16) & 1u)) >> 16;  // RNE
        float mf2 = __uint_as_float(mb << 16);
        float r2 = r1 - mf2;                                     // exact
        uint32_t u2 = __float_as_uint(r2);
        uint32_t lb = (u2 + 0x7FFFu + ((u2 >> 16) & 1u)) >> 16;  // exact fit
        hiT [n * KPAD + k] = (ushort)hb;
        midT[n * KPAD + k] = (ushort)mb;
        loT [n * KPAD + k] = (ushort)lb;
    }
}

// ---------------------------------------------------------------------------
// Fused spikegen + GEMM: I_all = bernoulli(x) @ W1 + b1.
// Phase 1 (prologue, no barriers): thread (er,eq) hashes its 8 bits for each
// of 25 slabs -> packed byte -> spkb[kw][block][tid] (coalesced, L2-res).
// Phase 2 (K-loop): [sync] -> issue B[kw] global_load_lds (hoisted ptrs) ->
// expand prefetched byte -> ds_write A frag -> prefetch byte kw+1 -> [sync]
// -> 48 MFMA. XOR-swizzled 16B quarters keep ds_read_b128 <=2-way.
// Accum order identical to R4/R6/R8/R12/R13 -> bitwise-identical I_all.
// ---------------------------------------------------------------------------
#define LDS_A  0
#define LDS_BH 4096
#define LDS_BM 20480
#define LDS_BL 36864

__global__ __launch_bounds__(256, 3) void fused_gemm_k(
        const ushort* __restrict__ hiT, const ushort* __restrict__ midT,
        const ushort* __restrict__ loT, const float* __restrict__ b1,
        const float* __restrict__ x, uint8_t* __restrict__ spkb,
        float* __restrict__ I_all) {
    __shared__ __align__(16) char lds[53248];

    const int tid = threadIdx.x;
    const int l   = tid & 63;
    const int wv  = tid >> 6;
    const int t   = blockIdx.x >> 6;     // 64 blocks per timestep
    const int b0  = (blockIdx.x & 63) << 6;
    const int m0  = blockIdx.x << 6;

    // A-expansion thread mapping: row er (0..63), byte-group eq (0..3)
    const int er = tid >> 2;
    const int eq = tid & 3;
    const int ea = LDS_A + (er << 6) + ((eq ^ (er & 3) ^ ((er >> 2) & 3)) << 4);
    const int row_b = b0 + er;

    // =====================================================================
    // Phase 1: hash all 25 slabs -> packed bytes (own data, no sync needed)
    // =====================================================================
    {
        const float* xq = x + (size_t)row_b * IN_DIM + (eq << 3);
        uint32_t ibq = (uint32_t)(row_b * IN_DIM) + (uint32_t)(eq << 3)
                     + (uint32_t)t * (uint32_t)(BATCH * IN_DIM);
        uint8_t* sb = spkb + (size_t)blockIdx.x * 256 + tid;
#pragma unroll 1
        for (int kw = 0; kw < KWORDS; ++kw) {
            uint32_t byte = 0u;
            if (!(kw == 24 && eq >= 2)) {    // k>=784 doesn't exist (+ OOB guard)
                float4 xa = *(const float4*)xq;
                float4 xb = *(const float4*)(xq + 4);
                uint32_t m0h, m1h, m2h, m3h, m4h, m5h, m6h, m7h;
                TF_HASH9(m0h, ibq, "42");
                TF_HASH9(m1h, ibq, "43");
                TF_HASH9(m2h, ibq, "44");
                TF_HASH9(m3h, ibq, "45");
                TF_HASH9(m4h, ibq, "46");
                TF_HASH9(m5h, ibq, "47");
                TF_HASH9(m6h, ibq, "48");
                TF_HASH9(m7h, ibq, "49");
                byte  = ((float)m0h < xa.x * 8388608.0f) ?   1u : 0u;
                byte |= ((float)m1h < xa.y * 8388608.0f) ?   2u : 0u;
                byte |= ((float)m2h < xa.z * 8388608.0f) ?   4u : 0u;
                byte |= ((float)m3h < xa.w * 8388608.0f) ?   8u : 0u;
                byte |= ((float)m4h < xb.x * 8388608.0f) ?  16u : 0u;
                byte |= ((float)m5h < xb.y * 8388608.0f) ?  32u : 0u;
                byte |= ((float)m6h < xb.z * 8388608.0f) ?  64u : 0u;
                byte |= ((float)m7h < xb.w * 8388608.0f) ? 128u : 0u;
            }
            sb[(size_t)kw * (NBLK * 256)] = (uint8_t)byte;
            xq += 32;  ibq += 32u;
        }
    }

    // =====================================================================
    // Phase 2: pure-MFMA K-loop
    // =====================================================================
    f32x4 acc[4][4] = {};

    // fragment read addressing (shared swizzle sig for A and B)
    const int q   = l >> 4;
    const int sig = q ^ (l & 3) ^ ((l >> 2) & 3);
    const int a_base = LDS_A + ((l & 15) << 6) + (sig << 4);
    const int b_off  = (((wv << 6) + (l & 15)) << 6) + (sig << 4);

    // loop-invariant staging addresses
    const ushort* hi_p[4];
    const ushort* md_p[4];
    const ushort* lo_p[4];
    int ldst_c[4];
#pragma unroll
    for (int i = 0; i < 4; ++i) {
        int s  = (wv << 8) + (i << 6) + l;
        int n  = s >> 2;
        int qs = s & 3;
        int qd = qs ^ (n & 3) ^ ((n >> 2) & 3);
        size_t eoff = (size_t)n * KPAD + ((size_t)qd << 3);
        hi_p[i] = hiT  + eoff;
        md_p[i] = midT + eoff;
        lo_p[i] = loT  + eoff;
        ldst_c[i] = ((wv << 8) + (i << 6)) << 4;
    }

    const uint8_t* sbp = spkb + (size_t)blockIdx.x * 256 + tid;
    uint32_t cur = sbp[0];               // prefetch slab 0's byte

    for (int kw = 0; kw < KWORDS; ++kw) {
        __syncthreads();   // previous compute done with LDS

        // --- stage Bhi/Bmid/Blo K-slab (hoisted pointers) ---
#pragma unroll
        for (int i = 0; i < 4; ++i) {
            __builtin_amdgcn_global_load_lds(
                (const __attribute__((address_space(1))) void*)hi_p[i],
                (__attribute__((address_space(3))) void*)(lds + LDS_BH + ldst_c[i]),
                16, 0, 0);
            __builtin_amdgcn_global_load_lds(
                (const __attribute__((address_space(1))) void*)md_p[i],
                (__attribute__((address_space(3))) void*)(lds + LDS_BM + ldst_c[i]),
                16, 0, 0);
            __builtin_amdgcn_global_load_lds(
                (const __attribute__((address_space(1))) void*)lo_p[i],
                (__attribute__((address_space(3))) void*)(lds + LDS_BL + ldst_c[i]),
                16, 0, 0);
            hi_p[i] += 32;  md_p[i] += 32;  lo_p[i] += 32;
        }

        // --- expand packed byte -> bf16 A fragment (16 B), ds_write ---
        {
            uint32_t b = cur;
            u32x4 v;
            v.x = ((b &   1u) ? 0x3F80u : 0u) | ((b &   2u) ? 0x3F800000u : 0u);
            v.y = ((b &   4u) ? 0x3F80u : 0u) | ((b &   8u) ? 0x3F800000u : 0u);
            v.z = ((b &  16u) ? 0x3F80u : 0u) | ((b &  32u) ? 0x3F800000u : 0u);
            v.w = ((b &  64u) ? 0x3F80u : 0u) | ((b & 128u) ? 0x3F800000u : 0u);
            *(u32x4*)(lds + ea) = v;
        }
        if (kw + 1 < KWORDS)
            cur = sbp[(size_t)(kw + 1) * (NBLK * 256)];   // prefetch next byte

        __syncthreads();   // A visible + global_load_lds drained

        // --- compute: 4 mtiles x 4 ntiles x (hi,mid,lo) = 48 MFMA ---
        bf16x8 af[4];
#pragma unroll
        for (int mt = 0; mt < 4; ++mt)
            af[mt] = *(const bf16x8*)(lds + a_base + (mt << 10));
#pragma unroll
        for (int nt = 0; nt < 4; ++nt) {
            bf16x8 bh = *(const bf16x8*)(lds + LDS_BH + b_off + (nt << 10));
            bf16x8 bm = *(const bf16x8*)(lds + LDS_BM + b_off + (nt << 10));
            bf16x8 bl = *(const bf16x8*)(lds + LDS_BL + b_off + (nt << 10));
#pragma unroll
            for (int mt = 0; mt < 4; ++mt) {
                acc[mt][nt] = __builtin_amdgcn_mfma_f32_16x16x32_bf16(af[mt], bh, acc[mt][nt], 0, 0, 0);
                acc[mt][nt] = __builtin_amdgcn_mfma_f32_16x16x32_bf16(af[mt], bm, acc[mt][nt], 0, 0, 0);
                acc[mt][nt] = __builtin_amdgcn_mfma_f32_16x16x32_bf16(af[mt], bl, acc[mt][nt], 0, 0, 0);
            }
        }
    }

    // --- epilogue: acc -> I_all (+ b1) ---
    const int c0 = l & 15;
    float b1v[4];
#pragma unroll
    for (int nt = 0; nt < 4; ++nt)
        b1v[nt] = b1[(wv << 6) + (nt << 4) + c0];
#pragma unroll
    for (int mt = 0; mt < 4; ++mt) {
#pragma unroll
        for (int nt = 0; nt < 4; ++nt) {
            int col = (wv << 6) + (nt << 4) + c0;
#pragma unroll
            for (int r = 0; r < 4; ++r) {
                int row = m0 + (mt << 4) + (q << 2) + r;
                I_all[(size_t)row * HID + col] = acc[mt][nt][r] + b1v[nt];
            }
        }
    }
}

// ---------------------------------------------------------------------------
// Fused LIF scan + readout: per block, 16 batch rows.
// ---------------------------------------------------------------------------
__global__ __launch_bounds__(256) void scanout_k(
        const float* __restrict__ I_all, const float* __restrict__ Wr,
        const float* __restrict__ br, float* __restrict__ out) {
    __shared__ float gl[16 * 256];       // 16 KB
    const int tid = threadIdx.x;
    const int b0  = blockIdx.x << 4;

#pragma unroll 4
    for (int b = 0; b < 16; ++b) {
        const float* p = I_all + ((size_t)(b0 + b) << 8) + tid;
        float v = 0.f, ga = 0.f, wt = 0.0009765625f;   // 2^-10
#pragma unroll
        for (int t = 0; t < T_STEPS; ++t) {
            float I = p[(size_t)t * BATCH * HID];
            v = v + (I - v) * 0.5f;
            if (v >= 1.0f) { ga += wt; v = 0.f; }
            wt += wt;
        }
        gl[(b << 8) + tid] = ga;
    }
    __syncthreads();

    const int wv = tid >> 6;
    const int c  = tid & 63;
    if (c >= NCLS) return;
    float acc[4] = {0.f, 0.f, 0.f, 0.f};
    for (int h4 = 0; h4 < 64; ++h4) {
        float w0 = Wr[((h4 << 2) + 0) * NCLS + c];
        float w1 = Wr[((h4 << 2) + 1) * NCLS + c];
        float w2 = Wr[((h4 << 2) + 2) * NCLS + c];
        float w3 = Wr[((h4 << 2) + 3) * NCLS + c];
#pragma unroll
        for (int j = 0; j < 4; ++j) {
            float4 gg = *(float4*)&gl[(((wv << 2) + j) << 8) + (h4 << 2)];
            acc[j] = fmaf(gg.x, w0, acc[j]);
            acc[j] = fmaf(gg.y, w1, acc[j]);
            acc[j] = fmaf(gg.z, w2, acc[j]);
            acc[j] = fmaf(gg.w, w3, acc[j]);
        }
    }
    float brv = br[c] * 0.9990234375f;
#pragma unroll
    for (int j = 0; j < 4; ++j)
        out[(b0 + (wv << 2) + j) * NCLS + c] = acc[j] + brv;
}

extern "C" void kernel_launch(void* const* d_in, const int* in_sizes, int n_in,
                              void* d_out, int out_size, void* d_ws, size_t ws_size,
                              hipStream_t stream) {
    const float* x  = (const float*)d_in[0];
    const float* W1 = (const float*)d_in[1];
    const float* b1 = (const float*)d_in[2];
    const float* Wr = (const float*)d_in[3];
    const float* br = (const float*)d_in[4];
    float* out = (float*)d_out;

    float*   I_all = (float*)  ((char*)d_ws + WS_IALL_OFF);
    uint8_t* spkb  = (uint8_t*)((char*)d_ws + WS_SPKB_OFF);
    ushort*  w1hi  = (ushort*) ((char*)d_ws + WS_W1HI_OFF);
    ushort*  w1md  = (ushort*) ((char*)d_ws + WS_W1MD_OFF);
    ushort*  w1lo  = (ushort*) ((char*)d_ws + WS_W1LO_OFF);

    splitk_k<<<HID, 256, 0, stream>>>(W1, w1hi, w1md, w1lo);
    fused_gemm_k<<<NBLK, 256, 0, stream>>>(w1hi, w1md, w1lo, b1, x, spkb, I_all);
    scanout_k<<<BATCH / 16, 256, 0, stream>>>(I_all, Wr, br, out);
}

// Round 16
// 206.367 us; speedup vs baseline: 1.1057x; 1.1057x over previous
//
#include <hip/hip_runtime.h>
#include <stdint.h>

// ---------------------------------------------------------------------------
// SNN EMNIST forward: T=10, B=4096, IN=784, HID=256, NCLS=47
// R16 = R15 with the SPIKE8 macro-hygiene fix (param renamed w -> wrd; the
// old name collided with float4 member access .w under the preprocessor).
// Structure: hash<->MFMA overlap is unattainable in one kernel (R6-R14), so
// split into individually-optimal kernels:
//   1) spike_split_k: R5's high-TLP spikegen grid (2000 blocks) + R13's
//      72-instr single-asm-block hash; blocks 2000..2255 do the exact 3-way
//      bf16 W1 split (independent work, hidden under spikegen).
//   2) gemm_mfma_k: R5's word-expand MFMA gemm VERBATIM (N=128, 5 blk/CU,
//      bitwise-validated, <72 us measured).
//   3) scanout_k: fused LIF scan + readout (R8-validated).
// All bit-paths previously validated -> absmax exactly 4.882812e-4.
// ---------------------------------------------------------------------------

#define T_STEPS 10
#define BATCH   4096
#define IN_DIM  784
#define HID     256
#define NCLS    47
#define NROWS   (T_STEPS * BATCH)        // 40960
#define KWORDS  25                       // ceil(784/32)
#define KPAD    800                      // 25*32

// d_ws layout (bytes):
//   [0, 41943040)          I_all : float [40960][256]
//   [41943040, 46039040)   spk   : u32 [25][10][4096]
//   [46039040, ...)        W1{hi,mid,lo}T : bf16 [256][800], 409600 B each
#define WS_IALL_OFF 0u
#define WS_SPK_OFF  41943040u
#define WS_W1HI_OFF 46039040u
#define WS_W1MD_OFF (46039040u + 409600u)
#define WS_W1LO_OFF (46039040u + 819200u)

typedef __attribute__((ext_vector_type(8))) short    bf16x8;
typedef __attribute__((ext_vector_type(4))) float    f32x4;
typedef __attribute__((ext_vector_type(4))) uint32_t u32x4;

// ---------------------------------------------------------------------------
// Threefry2x32, key=(0,42), partitionable: counter=(0, lo), out=(o0^o1)>>9.
// One asm block = whole hash (72 instrs), bitwise-validated in R13/R14.
// J42 = "42".."49" bakes element offset j (0..7) into the first add.
// ---------------------------------------------------------------------------
#define TF_G1(x0, x1) \
    "v_add_u32 " x0 ", " x0 ", " x1 "\n\t" \
    "v_alignbit_b32 " x1 ", " x1 ", " x1 ", 19\n\t" \
    "v_xor_b32 " x1 ", " x1 ", " x0 "\n\t" \
    "v_add_u32 " x0 ", " x0 ", " x1 "\n\t" \
    "v_alignbit_b32 " x1 ", " x1 ", " x1 ", 17\n\t" \
    "v_xor_b32 " x1 ", " x1 ", " x0 "\n\t" \
    "v_add_u32 " x0 ", " x0 ", " x1 "\n\t" \
    "v_alignbit_b32 " x1 ", " x1 ", " x1 ", 6\n\t" \
    "v_xor_b32 " x1 ", " x1 ", " x0 "\n\t" \
    "v_add_u32 " x0 ", " x0 ", " x1 "\n\t" \
    "v_alignbit_b32 " x1 ", " x1 ", " x1 ", 26\n\t" \
    "v_xor_b32 " x1 ", " x1 ", " x0 "\n\t"

#define TF_G2(x0, x1) \
    "v_add_u32 " x0 ", " x0 ", " x1 "\n\t" \
    "v_alignbit_b32 " x1 ", " x1 ", " x1 ", 15\n\t" \
    "v_xor_b32 " x1 ", " x1 ", " x0 "\n\t" \
    "v_add_u32 " x0 ", " x0 ", " x1 "\n\t" \
    "v_alignbit_b32 " x1 ", " x1 ", " x1 ", 3\n\t" \
    "v_xor_b32 " x1 ", " x1 ", " x0 "\n\t" \
    "v_add_u32 " x0 ", " x0 ", " x1 "\n\t" \
    "v_alignbit_b32 " x1 ", " x1 ", " x1 ", 16\n\t" \
    "v_xor_b32 " x1 ", " x1 ", " x0 "\n\t" \
    "v_add_u32 " x0 ", " x0 ", " x1 "\n\t" \
    "v_alignbit_b32 " x1 ", " x1 ", " x1 ", 8\n\t" \
    "v_xor_b32 " x1 ", " x1 ", " x0 "\n\t"

#define TF_HASH9(m, ib, J42) do {                                   \
    uint32_t _x0, _x1;                                              \
    asm("v_add_u32 %1, " J42 ", %2\n\t"       /* x1 = ib + 42+j */  \
        "v_mov_b32 %0, %1\n\t"                /* R1: x0 += x1   */  \
        "v_alignbit_b32 %1, %1, %1, 19\n\t"                         \
        "v_xor_b32 %1, %1, %0\n\t"                                  \
        "v_add_u32 %0, %0, %1\n\t"            /* R2 */              \
        "v_alignbit_b32 %1, %1, %1, 17\n\t"                         \
        "v_xor_b32 %1, %1, %0\n\t"                                  \
        "v_add_u32 %0, %0, %1\n\t"            /* R3 */              \
        "v_alignbit_b32 %1, %1, %1, 6\n\t"                          \
        "v_xor_b32 %1, %1, %0\n\t"                                  \
        "v_add_u32 %0, %0, %1\n\t"            /* R4 */              \
        "v_alignbit_b32 %1, %1, %1, 26\n\t"                         \
        "v_xor_b32 %1, %1, %0\n\t"                                  \
        "v_add_u32 %0, 42, %0\n\t"            /* x0 += ks1 */       \
        "v_add_u32 %1, 0x1bd11bf1, %1\n\t"    /* x1 += ks2+1 */     \
        TF_G2("%0", "%1")                     /* R5-R8 */           \
        "v_add_u32 %0, 0x1bd11bf0, %0\n\t"    /* x0 += ks2 */       \
        "v_add_u32 %1, 2, %1\n\t"             /* x1 += ks0+2 */     \
        TF_G1("%0", "%1")                     /* R9-R12 */          \
        "v_add_u32 %1, 45, %1\n\t"            /* x1 += ks1+3 */     \
        TF_G2("%0", "%1")                     /* R13-R16 */         \
        "v_add_u32 %0, 42, %0\n\t"            /* x0 += ks1 */       \
        "v_add_u32 %1, 0x1bd11bf4, %1\n\t"    /* x1 += ks2+4 */     \
        TF_G1("%0", "%1")                     /* R17-R20 */         \
        "v_add_u32 %0, 0x1bd11bf0, %0\n\t"    /* x0 += ks2 */       \
        "v_add_u32 %1, 5, %1\n\t"             /* x1 += ks0+5 */     \
        "v_xor_b32 %0, %0, %1\n\t"            /* o0^o1 */           \
        "v_lshrrev_b32 %0, 9, %0"             /* >>9 */             \
        : "=&v"(_x0), "=&v"(_x1) : "v"(ib));                        \
    m = _x0;                                                        \
} while (0)

// 8 hashes (j=0..7) at base ib, comparing vs xa/xb, OR-ing bits into wrd at
// bit positions base_bit..base_bit+7 (base_bit is a compile-time constant).
// NOTE: param must NOT be named 'w' — it would collide with .w member access.
#define SPIKE8(wrd, ib, xa, xb, base_bit) do {                             \
    uint32_t m0h, m1h, m2h, m3h, m4h, m5h, m6h, m7h;                       \
    TF_HASH9(m0h, (ib), "42");  TF_HASH9(m1h, (ib), "43");                 \
    TF_HASH9(m2h, (ib), "44");  TF_HASH9(m3h, (ib), "45");                 \
    TF_HASH9(m4h, (ib), "46");  TF_HASH9(m5h, (ib), "47");                 \
    TF_HASH9(m6h, (ib), "48");  TF_HASH9(m7h, (ib), "49");                 \
    if ((float)m0h < (xa).x * 8388608.0f) wrd |= (1u << ((base_bit) + 0)); \
    if ((float)m1h < (xa).y * 8388608.0f) wrd |= (1u << ((base_bit) + 1)); \
    if ((float)m2h < (xa).z * 8388608.0f) wrd |= (1u << ((base_bit) + 2)); \
    if ((float)m3h < (xa).w * 8388608.0f) wrd |= (1u << ((base_bit) + 3)); \
    if ((float)m4h < (xb).x * 8388608.0f) wrd |= (1u << ((base_bit) + 4)); \
    if ((float)m5h < (xb).y * 8388608.0f) wrd |= (1u << ((base_bit) + 5)); \
    if ((float)m6h < (xb).z * 8388608.0f) wrd |= (1u << ((base_bit) + 6)); \
    if ((float)m7h < (xb).w * 8388608.0f) wrd |= (1u << ((base_bit) + 7)); \
} while (0)

// ---------------------------------------------------------------------------
// Kernel 1: spikegen (blocks 0..1999, R5 grid) + W1 split (blocks 2000..2255).
// spikegen thread = (kw, tg, b): tg covers t = {2tg, 2tg+1}; writes 2 words
// spk[(kw*10+t)*4096 + b]. kw==24 upper 16 bits stay 0 (k>=784 absent).
// splitk: EXACT hi+mid+lo == w bitwise (two Sterbenz-exact subtractions).
// ---------------------------------------------------------------------------
__global__ __launch_bounds__(256) void spike_split_k(
        const float* __restrict__ x, uint32_t* __restrict__ spk,
        const float* __restrict__ W1, ushort* __restrict__ hiT,
        ushort* __restrict__ midT, ushort* __restrict__ loT) {
    const int tid = threadIdx.x;

    if (blockIdx.x >= 2000) {            // ---- W1 split ----
        int n = blockIdx.x - 2000;       // 0..255
        for (int k = tid; k < KPAD; k += 256) {
            float w = (k < IN_DIM) ? W1[k * HID + n] : 0.0f;
            uint32_t u = __float_as_uint(w);
            uint32_t hb = (u + 0x7FFFu + ((u >> 16) & 1u)) >> 16;    // RNE
            float hf = __uint_as_float(hb << 16);
            float r1 = w - hf;                                       // exact
            uint32_t u1 = __float_as_uint(r1);
            uint32_t mb = (u1 + 0x7FFFu + ((u1 >> 16) & 1u)) >> 16;  // RNE
            float mf2 = __uint_as_float(mb << 16);
            float r2 = r1 - mf2;                                     // exact
            uint32_t u2 = __float_as_uint(r2);
            uint32_t lb = (u2 + 0x7FFFu + ((u2 >> 16) & 1u)) >> 16;  // exact
            hiT [n * KPAD + k] = (ushort)hb;
            midT[n * KPAD + k] = (ushort)mb;
            loT [n * KPAD + k] = (ushort)lb;
        }
        return;
    }

    // ---- spikegen ----
    const int bid = blockIdx.x;          // (kw*5 + tg)*16 + bblk
    const int kw  = bid / 80;
    const int rem = bid - kw * 80;
    const int tg  = rem >> 4;
    const int b   = ((rem & 15) << 8) + tid;
    const int t0  = tg << 1;
    const int kbase = kw << 5;

    const uint32_t tstep = (uint32_t)(BATCH * IN_DIM);
    const uint32_t i0 = (uint32_t)(b * IN_DIM + kbase) + (uint32_t)t0 * tstep;
    const float* xr = x + b * IN_DIM + kbase;

    uint32_t w0 = 0u, w1 = 0u;
    const int ng = (kw == 24) ? 2 : 4;   // groups of 8 k's (wave-uniform)

    for (int g = 0; g < ng; ++g) {
        float4 xa = *(const float4*)&xr[g << 3];
        float4 xb = *(const float4*)&xr[(g << 3) + 4];
        uint32_t ib0 = i0 + (uint32_t)(g << 3);
        uint32_t ib1 = ib0 + tstep;
        switch (g) {                     // base_bit must be compile-time
            case 0: SPIKE8(w0, ib0, xa, xb, 0);  SPIKE8(w1, ib1, xa, xb, 0);  break;
            case 1: SPIKE8(w0, ib0, xa, xb, 8);  SPIKE8(w1, ib1, xa, xb, 8);  break;
            case 2: SPIKE8(w0, ib0, xa, xb, 16); SPIKE8(w1, ib1, xa, xb, 16); break;
            default:SPIKE8(w0, ib0, xa, xb, 24); SPIKE8(w1, ib1, xa, xb, 24); break;
        }
    }
    spk[(kw * T_STEPS + t0    ) * BATCH + b] = w0;
    spk[(kw * T_STEPS + t0 + 1) * BATCH + b] = w1;
}

// ---------------------------------------------------------------------------
// Kernel 2: gemm from packed words (R5's validated kernel, verbatim).
// Block: 64 rows (one t) x 128 cols, 4 waves; wave = 64x32 = 4x2 tiles of
// 16x16x32. Grid 1280 = exactly 5 blocks/CU, LDS 28KB.
// ---------------------------------------------------------------------------
#define LDS_A  0
#define LDS_BH 4096
#define LDS_BM 12288
#define LDS_BL 20480

__global__ __launch_bounds__(256, 5) void gemm_mfma_k(
        const ushort* __restrict__ hiT, const ushort* __restrict__ midT,
        const ushort* __restrict__ loT, const float* __restrict__ b1,
        const uint32_t* __restrict__ spk, float* __restrict__ I_all) {
    __shared__ __align__(16) char lds[28672];

    const int tid = threadIdx.x;
    const int l   = tid & 63;
    const int wv  = tid >> 6;
    const int bid = blockIdx.x;
    const int t    = bid >> 7;           // 128 blocks per t
    const int rem  = bid & 127;
    const int b0   = (rem >> 1) << 6;
    const int nc0  = (rem & 1) << 7;     // col offset 0 or 128
    const int m0   = (t << 12) + b0;

    f32x4 acc[4][2] = {};

    const int q   = l >> 4;
    const int sig = q ^ (l & 3) ^ ((l >> 2) & 3);
    const int a_base = LDS_A + ((l & 15) << 6) + (sig << 4);
    const int b_base = (((wv << 5) + (l & 15)) << 6) + (sig << 4);

    const int er = tid >> 2;
    const int eq = tid & 3;
    const int ea = LDS_A + (er << 6) + ((eq ^ (er & 3) ^ ((er >> 2) & 3)) << 4);
    const uint32_t* wptr = spk + (size_t)t * BATCH + b0 + er;

    for (int kw = 0; kw < KWORDS; ++kw) {
        __syncthreads();

        // --- stage Bhi/Bmid/Blo chunk (k in [kw*32,kw*32+32), 128 n) ---
#pragma unroll
        for (int i = 0; i < 2; ++i) {
            int s  = (i << 8) + tid;                    // slot 0..511
            int n  = s >> 2;
            int qs = s & 3;
            int qd = qs ^ (n & 3) ^ ((n >> 2) & 3);
            size_t gb = (size_t)(nc0 + n) * (KPAD * 2) + ((size_t)kw << 6) + ((size_t)qd << 4);
            int ldst = s << 4;
            __builtin_amdgcn_global_load_lds(
                (const __attribute__((address_space(1))) void*)((const char*)hiT + gb),
                (__attribute__((address_space(3))) void*)(lds + LDS_BH + ldst),
                16, 0, 0);
            __builtin_amdgcn_global_load_lds(
                (const __attribute__((address_space(1))) void*)((const char*)midT + gb),
                (__attribute__((address_space(3))) void*)(lds + LDS_BM + ldst),
                16, 0, 0);
            __builtin_amdgcn_global_load_lds(
                (const __attribute__((address_space(1))) void*)((const char*)loT + gb),
                (__attribute__((address_space(3))) void*)(lds + LDS_BL + ldst),
                16, 0, 0);
        }

        // --- expand spike bits -> bf16 A tile (64 rows x 32 k) ---
        {
            uint32_t w = wptr[(size_t)kw * NROWS];
            uint32_t byte = (w >> (eq << 3)) & 0xFFu;
            u32x4 v;
            v.x = ((byte &   1u) ? 0x3F80u : 0u) | ((byte &   2u) ? 0x3F800000u : 0u);
            v.y = ((byte &   4u) ? 0x3F80u : 0u) | ((byte &   8u) ? 0x3F800000u : 0u);
            v.z = ((byte &  16u) ? 0x3F80u : 0u) | ((byte &  32u) ? 0x3F800000u : 0u);
            v.w = ((byte &  64u) ? 0x3F80u : 0u) | ((byte & 128u) ? 0x3F800000u : 0u);
            *(u32x4*)(lds + ea) = v;
        }

        __syncthreads();

        // --- compute: 4 mtiles x 2 ntiles x (hi,mid,lo) = 24 MFMA ---
        bf16x8 af[4];
#pragma unroll
        for (int mt = 0; mt < 4; ++mt)
            af[mt] = *(const bf16x8*)(lds + a_base + (mt << 10));
#pragma unroll
        for (int nt = 0; nt < 2; ++nt) {
            bf16x8 bh = *(const bf16x8*)(lds + LDS_BH + b_base + (nt << 10));
            bf16x8 bm = *(const bf16x8*)(lds + LDS_BM + b_base + (nt << 10));
            bf16x8 bl = *(const bf16x8*)(lds + LDS_BL + b_base + (nt << 10));
#pragma unroll
            for (int mt = 0; mt < 4; ++mt) {
                acc[mt][nt] = __builtin_amdgcn_mfma_f32_16x16x32_bf16(af[mt], bh, acc[mt][nt], 0, 0, 0);
                acc[mt][nt] = __builtin_amdgcn_mfma_f32_16x16x32_bf16(af[mt], bm, acc[mt][nt], 0, 0, 0);
                acc[mt][nt] = __builtin_amdgcn_mfma_f32_16x16x32_bf16(af[mt], bl, acc[mt][nt], 0, 0, 0);
            }
        }
    }

    // --- epilogue: acc -> I_all (+ b1) ---
    const int c0 = l & 15;
    float b1v[2];
#pragma unroll
    for (int nt = 0; nt < 2; ++nt)
        b1v[nt] = b1[nc0 + (wv << 5) + (nt << 4) + c0];
#pragma unroll
    for (int mt = 0; mt < 4; ++mt) {
#pragma unroll
        for (int nt = 0; nt < 2; ++nt) {
            int col = nc0 + (wv << 5) + (nt << 4) + c0;
#pragma unroll
            for (int r = 0; r < 4; ++r) {
                int row = m0 + (mt << 4) + (q << 2) + r;
                I_all[(size_t)row * HID + col] = acc[mt][nt][r] + b1v[nt];
            }
        }
    }
}

// ---------------------------------------------------------------------------
// Kernel 3: fused LIF scan + readout (R8-validated), 16 batch rows/block.
// ---------------------------------------------------------------------------
__global__ __launch_bounds__(256) void scanout_k(
        const float* __restrict__ I_all, const float* __restrict__ Wr,
        const float* __restrict__ br, float* __restrict__ out) {
    __shared__ float gl[16 * 256];       // 16 KB
    const int tid = threadIdx.x;
    const int b0  = blockIdx.x << 4;

#pragma unroll 4
    for (int b = 0; b < 16; ++b) {
        const float* p = I_all + ((size_t)(b0 + b) << 8) + tid;
        float v = 0.f, ga = 0.f, wt = 0.0009765625f;   // 2^-10
#pragma unroll
        for (int t = 0; t < T_STEPS; ++t) {
            float I = p[(size_t)t * BATCH * HID];
            v = v + (I - v) * 0.5f;
            if (v >= 1.0f) { ga += wt; v = 0.f; }
            wt += wt;
        }
        gl[(b << 8) + tid] = ga;
    }
    __syncthreads();

    const int wv = tid >> 6;
    const int c  = tid & 63;
    if (c >= NCLS) return;
    float acc[4] = {0.f, 0.f, 0.f, 0.f};
    for (int h4 = 0; h4 < 64; ++h4) {
        float w0 = Wr[((h4 << 2) + 0) * NCLS + c];
        float w1 = Wr[((h4 << 2) + 1) * NCLS + c];
        float w2 = Wr[((h4 << 2) + 2) * NCLS + c];
        float w3 = Wr[((h4 << 2) + 3) * NCLS + c];
#pragma unroll
        for (int j = 0; j < 4; ++j) {
            float4 gg = *(float4*)&gl[(((wv << 2) + j) << 8) + (h4 << 2)];
            acc[j] = fmaf(gg.x, w0, acc[j]);
            acc[j] = fmaf(gg.y, w1, acc[j]);
            acc[j] = fmaf(gg.z, w2, acc[j]);
            acc[j] = fmaf(gg.w, w3, acc[j]);
        }
    }
    float brv = br[c] * 0.9990234375f;
#pragma unroll
    for (int j = 0; j < 4; ++j)
        out[(b0 + (wv << 2) + j) * NCLS + c] = acc[j] + brv;
}

extern "C" void kernel_launch(void* const* d_in, const int* in_sizes, int n_in,
                              void* d_out, int out_size, void* d_ws, size_t ws_size,
                              hipStream_t stream) {
    const float* x  = (const float*)d_in[0];
    const float* W1 = (const float*)d_in[1];
    const float* b1 = (const float*)d_in[2];
    const float* Wr = (const float*)d_in[3];
    const float* br = (const float*)d_in[4];
    float* out = (float*)d_out;

    float*    I_all = (float*)   ((char*)d_ws + WS_IALL_OFF);
    uint32_t* spk   = (uint32_t*)((char*)d_ws + WS_SPK_OFF);
    ushort*   w1hi  = (ushort*)  ((char*)d_ws + WS_W1HI_OFF);
    ushort*   w1md  = (ushort*)  ((char*)d_ws + WS_W1MD_OFF);
    ushort*   w1lo  = (ushort*)  ((char*)d_ws + WS_W1LO_OFF);

    spike_split_k<<<2256, 256, 0, stream>>>(x, spk, W1, w1hi, w1md, w1lo);
    gemm_mfma_k<<<1280, 256, 0, stream>>>(w1hi, w1md, w1lo, b1, spk, I_all);
    scanout_k<<<BATCH / 16, 256, 0, stream>>>(I_all, Wr, br, out);
}